// Round 1
// 263.983 us; speedup vs baseline: 1.0210x; 1.0210x over previous
//
#include <hip/hip_runtime.h>

// RoiPooling via integral image, fused single-pass scan:
//  fusedScanK: fm (C,H,W) -> S[y][x][c] channel-last, where each y-chunk of 8
//              rows holds a LOCAL 2D integral (row-scan full-x, col-scan local
//              to chunk). Zero borders (y=0 row, x=0 col) written inline.
//  offsetK   : OP[k][x][c] = fp64 prefix over the 31 chunk totals (17 MB, L3).
//  gatherK   : corner value = S_local[ry][rx] + OP[chunk(ry)][rx]; 9-corner
//              per-ROI gather, 4-corner difference per patch.
//
// ws layout (floats):
//   S  @ 0          size 257*257*512 = 33,817,088  (135.3 MB)
//   OP @ 33817088   size  33*257*512 =  4,341,760  ( 17.4 MB)

#define CHN 512
#define HD  256
#define WD  256
#define SP  257
#define YC  8                 // rows per y-chunk
#define NK  32                // number of y-chunks
#define OP_OFF 33817088UL

// ---------------- fused scan: fm -> S (chunk-local integral) ---------------
// Block 512 thr (8 waves); tile = 32 c x 256 x x 8 y. Grid (16 ct, 32 k) =
// 512 blocks = 2 blocks/CU (LDS 66.5 KB x2 = 133 KB fits). 16 waves/CU vs the
// previous 8: prior version (256 thr) measured OccupancyPercent 15.8 /
// VALUBusy 7.3 / 2.2 TB/s -> latency-bound, not BW-bound. Each wave now owns
// 4 channels (was 8); per-channel arithmetic order is UNCHANGED (bit-identical
// S, absmax budget is fully consumed at 0.00195).
// Per y: dense 1KB/wave loads, wave-shuffle row scan, LDS transpose (double
// buffered, ONE barrier per y), fp32 col-accumulate in store layout, dense
// 128B-segment channel-last stores.
__global__ __launch_bounds__(512, 4) void fusedScanK(const float* __restrict__ fm,
                                                     float* __restrict__ S) {
    __shared__ float tile[2][32][260];   // 260 pad: 16B-aligned rows, 4-way read worst
    const int t = threadIdx.x, lane = t & 63, w = t >> 6;   // w = wave 0..7
    const int c0 = blockIdx.x * 32;
    const int k  = blockIdx.y;
    const int y0 = k * YC;

    const int cg = t & 7;                // store: 4-channel group (8 groups = 32 ch)
    const int x8 = t >> 3;               // store: x mod 64
    const float4 z4 = make_float4(0.f, 0.f, 0.f, 0.f);

    if (k == 0) {                        // y=0 border row, x=0..255
        #pragma unroll
        for (int it = 0; it < 4; ++it) {
            const int lin = it * 512 + t;
            const int cgg = lin & 7, x = lin >> 3;
            *(float4*)(S + (size_t)x * CHN + c0 + 4 * cgg) = z4;
        }
    }

    float4 cur[4], nxt[4];
    #pragma unroll
    for (int j = 0; j < 4; ++j)
        cur[j] = *(const float4*)(fm + ((size_t)(c0 + w * 4 + j) << 16)
                                     + (size_t)y0 * 256 + 4 * lane);

    float4 acc[4];
    #pragma unroll
    for (int m = 0; m < 4; ++m) acc[m] = z4;

    for (int y = 0; y < YC; ++y) {
        const int buf = y & 1;
        if (y < YC - 1) {                // prefetch next row-block (in flight
            #pragma unroll               //  across scan + store phases)
            for (int j = 0; j < 4; ++j)
                nxt[j] = *(const float4*)(fm + ((size_t)(c0 + w * 4 + j) << 16)
                                             + (size_t)(y0 + y + 1) * 256 + 4 * lane);
        }
        // row scan: wave w handles channels w*4..w*4+3, full 256-x per row
        #pragma unroll
        for (int j = 0; j < 4; ++j) {
            const float4 v = cur[j];
            const float local = ((v.x + v.y) + v.z) + v.w;
            float s = local;
            #pragma unroll
            for (int d = 1; d < 64; d <<= 1) {
                float u = __shfl_up(s, d, 64);
                if (lane >= d) s += u;
            }
            const float e = s - local;   // exclusive lane prefix
            float4 p;
            p.x = e   + v.x;
            p.y = p.x + v.y;
            p.z = p.y + v.z;
            p.w = p.z + v.w;
            *(float4*)&tile[buf][w * 4 + j][4 * lane] = p;
        }
        __syncthreads();
        // col-accumulate + store: 8 lanes (cg 0..7) = 128B contiguous per x
        const size_t rowb = ((size_t)(y0 + y + 1) * SP) * CHN;
        #pragma unroll
        for (int m = 0; m < 4; ++m) {
            const int x = x8 + 64 * m;
            float4 a = acc[m];
            a.x += tile[buf][4 * cg + 0][x];
            a.y += tile[buf][4 * cg + 1][x];
            a.z += tile[buf][4 * cg + 2][x];
            a.w += tile[buf][4 * cg + 3][x];
            acc[m] = a;
            *(float4*)(S + rowb + (size_t)(x + 1) * CHN + c0 + 4 * cg) = a;
        }
        if (t < 8)                       // x=0 border for this row
            *(float4*)(S + rowb + c0 + 4 * t) = z4;
        #pragma unroll
        for (int j = 0; j < 4; ++j) cur[j] = nxt[j];
        // no second barrier: next y writes the other LDS buffer; y+2's reuse
        // of this buffer is ordered by the y+1 barrier.
    }
}

// ---------------- offsetK: fp64 prefix of chunk totals ---------------------
// OP[k][x][c], k=0..32; OP[0]=OP[1]=0; OP[k>=2] = sum of chunk totals 0..k-2.
// Chunk j total = S[y=8(j+1)][x][c] (last local row of chunk j).
__global__ __launch_bounds__(256) void offsetK(const float* __restrict__ S,
                                               float* __restrict__ OP) {
    const int gid = blockIdx.x * 256 + threadIdx.x;   // 0 .. 131583 exactly
    const int c = gid & 511, x = gid >> 9;            // x 0..256
    OP[((size_t)0 * SP + x) * CHN + c] = 0.0f;
    OP[((size_t)1 * SP + x) * CHN + c] = 0.0f;
    double run = 0.0;
    #pragma unroll
    for (int j = 0; j < NK - 1; ++j) {
        run += (double)S[((size_t)(YC * (j + 1)) * SP + x) * CHN + c];
        OP[((size_t)(j + 2) * SP + x) * CHN + c] = (float)run;
    }
}

// ---------------- gatherK: per-ROI 9-corner gather with offset add ---------
__global__ __launch_bounds__(256) void gatherK(const float* __restrict__ S,
                                              const float* __restrict__ OP,
                                              const float* __restrict__ roi,
                                              float* __restrict__ out,
                                              float* __restrict__ maskOut,
                                              int N) {
    const int n = blockIdx.x;
    const float xmin = roi[4 * n + 0];
    const float ymin = roi[4 * n + 1];
    const float xmax = roi[4 * n + 2];
    const float ymax = roi[4 * n + 3];

    // Replicate np fp32 op order exactly (no fma contraction).
    const float wsv = __fdiv_rn(__fsub_rn(xmax, xmin), 2.0f);
    const float hsv = __fdiv_rn(__fsub_rn(ymax, ymin), 2.0f);
    const float ax1 = __fadd_rn(xmin, wsv);
    const float ay1 = __fadd_rn(ymin, hsv);
    const float lim = (float)(WD - 1);

    int rx[3], ry[3];
    rx[0] = (int)fminf(fmaxf(rintf(xmin), 0.0f), lim);
    rx[1] = (int)fminf(fmaxf(rintf(ax1), 0.0f), lim);
    rx[2] = (int)fminf(fmaxf(rintf(__fadd_rn(ax1, wsv)), 0.0f), lim);
    ry[0] = (int)fminf(fmaxf(rintf(ymin), 0.0f), lim);
    ry[1] = (int)fminf(fmaxf(rintf(ay1), 0.0f), lim);
    ry[2] = (int)fminf(fmaxf(rintf(__fadd_rn(ay1, hsv)), 0.0f), lim);

    const int t = threadIdx.x;            // c-pair: channels 2t, 2t+1
    float2 g[3][3];
    #pragma unroll
    for (int j = 0; j < 3; ++j) {
        const int kk = (ry[j] + YC - 1) >> 3;   // chunk-offset row in OP
        #pragma unroll
        for (int i = 0; i < 3; ++i) {
            const float2 l = *(const float2*)(S  + ((size_t)ry[j] * SP + rx[i]) * CHN + 2 * t);
            const float2 o = *(const float2*)(OP + ((size_t)kk   * SP + rx[i]) * CHN + 2 * t);
            g[j][i] = make_float2(l.x + o.x, l.y + o.y);
        }
    }

    float m[4];
    #pragma unroll
    for (int p = 0; p < 4; ++p) {
        const int ix = p & 1, iy = p >> 1;
        const int cw = rx[ix + 1] - rx[ix];
        const int ch = ry[iy + 1] - ry[iy];
        const int maskv = (cw >= 1 && ch >= 1) ? 1 : 0;
        int areai = cw * ch; if (areai < 1) areai = 1;
        const float areaf = (float)areai;
        const float maskf = (float)maskv;
        m[p] = maskf;

        const float2 s11 = g[iy + 1][ix + 1];
        const float2 s01 = g[iy][ix + 1];
        const float2 s10 = g[iy + 1][ix];
        const float2 s00 = g[iy][ix];
        float2 o;  // reference order: ((S11 - S01) - S10) + S00, /area, *mask
        o.x = __fdiv_rn(((s11.x - s01.x) - s10.x) + s00.x, areaf) * maskf;
        o.y = __fdiv_rn(((s11.y - s01.y) - s10.y) + s00.y, areaf) * maskf;
        *(float2*)(out + ((size_t)p * N + n) * CHN + 2 * t) = o;
    }
    if (t < 4) maskOut[(size_t)t * N + n] = m[t];
}

// ---------------------------------------------------------------------------
extern "C" void kernel_launch(void* const* d_in, const int* in_sizes, int n_in,
                              void* d_out, int out_size, void* d_ws, size_t ws_size,
                              hipStream_t stream) {
    const float* fm  = (const float*)d_in[0];
    const float* roi = (const float*)d_in[1];
    // d_in[2] = patch_num (always 4 here); pe=2 hardcoded.

    const int N = in_sizes[1] / 4;     // 4096
    const int B = 4 * N;               // 16384

    float* S  = (float*)d_ws;
    float* OP = (float*)d_ws + OP_OFF;
    float* out     = (float*)d_out;
    float* maskOut = out + (size_t)B * CHN;

    dim3 gF(CHN / 32, NK);             // 16 x 32 = 512 blocks, 2/CU
    fusedScanK<<<gF, 512, 0, stream>>>(fm, S);

    offsetK<<<(SP * CHN) / 256, 256, 0, stream>>>(S, OP);   // 514 blocks

    gatherK<<<N, 256, 0, stream>>>(S, OP, roi, out, maskOut, N);
}